// Round 1
// 816.566 us; speedup vs baseline: 1.1185x; 1.1185x over previous
//
#include <hip/hip_runtime.h>
#include <math.h>

#define N_NODES 50000
#define N_EDGES 400000
#define IN_F 256
#define OUT_F 64
#define ED_F 64
#define NH 4

using f16x8 = __attribute__((ext_vector_type(8))) _Float16;
using f32x4 = __attribute__((ext_vector_type(4))) float;

// block 0: u[h][f] = sum_g W_eatt[h][f][g]*We[h][g]; c[h] = b_att[h] + b_eatt[h].We[h]
// blocks 1..32: Wfcfrag (f16, MFMA b-frag order), blocks 33..40: Wefrag
__global__ __launch_bounds__(256) void prep_kernel(
    const float* __restrict__ W_att, const float* __restrict__ b_att,
    const float* __restrict__ W_eatt, const float* __restrict__ b_eatt,
    const float* __restrict__ W_fc, const float* __restrict__ W_edge,
    float* __restrict__ u, float* __restrict__ c,
    _Float16* __restrict__ Wfcfrag, _Float16* __restrict__ Wefrag)
{
    const int b = blockIdx.x, t = threadIdx.x;
    if (b == 0) {
        int h = t >> 6, f = t & 63;
        const float* We = W_att + h * (2 * OUT_F + ED_F) + 2 * OUT_F;
        float s = 0.f;
        for (int g = 0; g < ED_F; g++) s += W_eatt[(h * ED_F + f) * ED_F + g] * We[g];
        u[t] = s;
        if (f == 0) {
            float cc = b_att[h];
            for (int g = 0; g < ED_F; g++) cc += b_eatt[h * ED_F + g] * We[g];
            c[h] = cc;
        }
    } else if (b <= 32) {
        // b_frag[lane][j] = B[k=quad*8+j][n=lane&15], B = W_fc[h] (256x64)
        int idx = b - 1;
        int h = idx >> 3, kt = idx & 7;
        int lane = t & 63, nt = t >> 6;
        int q = lane >> 4, l15 = lane & 15;
        f16x8 w;
#pragma unroll
        for (int j = 0; j < 8; j++) {
            int k = kt * 32 + q * 8 + j;
            int o = nt * 16 + l15;
            w[j] = (_Float16)W_fc[((size_t)h * IN_F + k) * OUT_F + o];
        }
        *(f16x8*)&Wfcfrag[(size_t)(((h * 8 + kt) * 4 + nt) * 64 + lane) * 8] = w;
    } else {
        int idx = b - 33;
        int h = idx >> 1, kt = idx & 1;
        int lane = t & 63, nt = t >> 6;
        int q = lane >> 4, l15 = lane & 15;
        f16x8 w;
#pragma unroll
        for (int j = 0; j < 8; j++) {
            int k = kt * 32 + q * 8 + j;
            int o = nt * 16 + l15;
            w[j] = (_Float16)W_edge[((size_t)h * ED_F + k) * OUT_F + o];
        }
        *(f16x8*)&Wefrag[(size_t)(((h * 2 + kt) * 4 + nt) * 64 + lane) * 8] = w;
    }
}

// z[h][n][o] = x@W_fc + b_fc, f16 MFMA 16x16x32. Block: 64 nodes, 4 waves = 4 heads.
__global__ __launch_bounds__(256) void z_gemm(
    const float* __restrict__ x, const _Float16* __restrict__ Wfcfrag,
    const float* __restrict__ b_fc, _Float16* __restrict__ zb)
{
    __shared__ _Float16 aLDS[32 * 64 * 8];   // 32 chunks(kt,quad) x 64 nodes x 8 f16 = 32KB
    const int t = threadIdx.x;
    const int n0 = blockIdx.x * 64;
    const int lane = t & 63, h = t >> 6;
    const int q = lane >> 4, l15 = lane & 15;

    // stage x tile (64 nodes x 256 k) fp32 -> f16 frag-order LDS
    {
        const int m = t >> 2, qq = t & 3;
        const int n = n0 + m;
#pragma unroll
        for (int p = 0; p < 4; p++) {
            float4 v4[4];
            if (n < N_NODES) {
                const float4* xp = (const float4*)(x + (size_t)n * IN_F + p * 64 + qq * 16);
#pragma unroll
                for (int k = 0; k < 4; k++) v4[k] = xp[k];
            } else {
#pragma unroll
                for (int k = 0; k < 4; k++) v4[k] = make_float4(0.f, 0.f, 0.f, 0.f);
            }
            const float* vv = (const float*)v4;
#pragma unroll
            for (int i = 0; i < 2; i++) {
                int c8 = p * 8 + qq * 2 + i;
                f16x8 w;
#pragma unroll
                for (int j = 0; j < 8; j++) w[j] = (_Float16)vv[i * 8 + j];
                *(f16x8*)&aLDS[(c8 * 64 + m) * 8] = w;
            }
        }
    }
    __syncthreads();

    f32x4 acc[4][4];
#pragma unroll
    for (int mt = 0; mt < 4; mt++)
#pragma unroll
        for (int nt = 0; nt < 4; nt++) acc[mt][nt] = (f32x4)0.f;

    for (int kt = 0; kt < 8; kt++) {
        f16x8 bfr[4];
#pragma unroll
        for (int nt = 0; nt < 4; nt++)
            bfr[nt] = *(const f16x8*)&Wfcfrag[(size_t)(((h * 8 + kt) * 4 + nt) * 64 + lane) * 8];
        f16x8 afr[4];
#pragma unroll
        for (int mt = 0; mt < 4; mt++)
            afr[mt] = *(f16x8*)&aLDS[((kt * 4 + q) * 64 + mt * 16 + l15) * 8];
#pragma unroll
        for (int mt = 0; mt < 4; mt++)
#pragma unroll
            for (int nt = 0; nt < 4; nt++)
                acc[mt][nt] = __builtin_amdgcn_mfma_f32_16x16x32_f16(afr[mt], bfr[nt], acc[mt][nt], 0, 0, 0);
    }

    float bfc[4];
#pragma unroll
    for (int nt = 0; nt < 4; nt++) bfc[nt] = b_fc[h * OUT_F + nt * 16 + l15];

    // C/D layout: col = lane&15, row = quad*4 + reg
#pragma unroll
    for (int mt = 0; mt < 4; mt++) {
#pragma unroll
        for (int r = 0; r < 4; r++) {
            int node = n0 + mt * 16 + q * 4 + r;
            if (node < N_NODES) {
                _Float16* zrow = zb + ((size_t)h * N_NODES + node) * OUT_F;
#pragma unroll
                for (int nt = 0; nt < 4; nt++)
                    zrow[nt * 16 + l15] = (_Float16)(acc[mt][nt][r] + bfc[nt]);
            }
        }
    }
}

// a_i/a_j = z . Wi / Wj (fp32 weights, f16 z). wave = head, 16 nodes/block.
__global__ __launch_bounds__(256) void a_ij_kernel(
    const _Float16* __restrict__ zb, const float* __restrict__ W_att,
    float* __restrict__ a_i, float* __restrict__ a_j)
{
    const int t = threadIdx.x, h = t >> 6, lane = t & 63;
    const float wi = W_att[h * 192 + lane];
    const float wj = W_att[h * 192 + 64 + lane];
    const int nb = blockIdx.x * 16;
    for (int i = 0; i < 16; i++) {
        int n = nb + i;
        float zv = (float)zb[((size_t)h * N_NODES + n) * OUT_F + lane];
        float pi = zv * wi, pj = zv * wj;
#pragma unroll
        for (int m = 32; m; m >>= 1) {
            pi += __shfl_xor(pi, m, 64);
            pj += __shfl_xor(pj, m, 64);
        }
        if (lane == 0) { a_i[h * N_NODES + n] = pi; a_j[h * N_NODES + n] = pj; }
    }
}

// --- counting-sort by dst -------------------------------------------------

__global__ __launch_bounds__(256) void hist_kernel(
    const int* __restrict__ edge_index, int* __restrict__ deg)
{
    const int e = blockIdx.x * 256 + threadIdx.x;
    if (e < N_EDGES) atomicAdd(&deg[edge_index[N_EDGES + e]], 1);
}

// single-block exclusive scan over deg[0..N) -> row_ptr[0..N], cursor copy
__global__ __launch_bounds__(256) void scan_kernel(
    const int* __restrict__ deg, int* __restrict__ row_ptr, int* __restrict__ cursor)
{
    __shared__ int wsum[4];
    const int t = threadIdx.x, lane = t & 63, w = t >> 6;
    int running = 0;
    const int nchunk = (N_NODES + 255) / 256;
    for (int ck = 0; ck < nchunk; ck++) {
        int idx = ck * 256 + t;
        int v = (idx < N_NODES) ? deg[idx] : 0;
        int x = v;
#pragma unroll
        for (int off = 1; off < 64; off <<= 1) {
            int y = __shfl_up(x, off, 64);
            if (lane >= off) x += y;
        }
        if (lane == 63) wsum[w] = x;
        __syncthreads();
        int woff = 0;
#pragma unroll
        for (int i = 0; i < 4; i++) if (i < w) woff += wsum[i];
        int tot = wsum[0] + wsum[1] + wsum[2] + wsum[3];
        int excl = running + woff + x - v;
        if (idx < N_NODES) { row_ptr[idx] = excl; cursor[idx] = excl; }
        running += tot;
        __syncthreads();
    }
    if (t == 0) row_ptr[N_NODES] = running;
}

__global__ __launch_bounds__(256) void scatter_kernel(
    const int* __restrict__ edge_index, int* __restrict__ cursor,
    int* __restrict__ epos, int* __restrict__ eorig,
    int* __restrict__ ssrc, int* __restrict__ sdst)
{
    const int e = blockIdx.x * 256 + threadIdx.x;
    if (e >= N_EDGES) return;
    const int d = edge_index[N_EDGES + e];
    const int pos = atomicAdd(&cursor[d], 1);
    epos[e] = pos;
    eorig[pos] = e;
    ssrc[pos] = edge_index[e];
    sdst[pos] = d;
}

// per edge: ev = leaky_relu(a_i[dst] + a_j[src] + edge_attr.u[h] + c[h]);
// written to dst-sorted position epos[e]. NO atomics.
__global__ __launch_bounds__(256) void logits_kernel(
    const int* __restrict__ edge_index, const float* __restrict__ edge_attr,
    const float* __restrict__ u, const float* __restrict__ c,
    const float* __restrict__ a_i, const float* __restrict__ a_j,
    const int* __restrict__ epos, float* __restrict__ eperm)
{
    const int t = threadIdx.x;
    const int lane = t & 63;
    const int w = t >> 6;
    const int e = blockIdx.x * 4 + w;
    const int src = edge_index[e];
    const int dst = edge_index[N_EDGES + e];
    const int pos = epos[e];
    const float ea = edge_attr[(size_t)e * ED_F + lane];
#pragma unroll
    for (int h = 0; h < NH; h++) {
        float p = ea * u[h * 64 + lane];
#pragma unroll
        for (int m = 32; m; m >>= 1) p += __shfl_xor(p, m, 64);
        if (lane == 0) {
            float a = p + a_i[h * N_NODES + dst] + a_j[h * N_NODES + src] + c[h];
            float ev = a > 0.f ? a : 0.2f * a;
            eperm[(size_t)h * N_EDGES + pos] = ev;
        }
    }
}

// per (node, head): serial softmax over the node's contiguous sorted run.
// Converts eperm logits -> alpha in place; scatters alpha to original order.
__global__ __launch_bounds__(256) void softmax_kernel(
    const int* __restrict__ row_ptr, const int* __restrict__ eorig,
    float* __restrict__ eperm, float* __restrict__ alpha_out)
{
    const int n = blockIdx.x * 256 + threadIdx.x;
    if (n >= N_NODES) return;
    const int b = row_ptr[n], en = row_ptr[n + 1];
    if (b >= en) return;
    const int h = blockIdx.y;
    float* ep = eperm + (size_t)h * N_EDGES;
    float* ao = alpha_out + (size_t)h * N_EDGES;
    float m = -INFINITY;
    for (int p = b; p < en; p++) m = fmaxf(m, ep[p]);
    float s = 0.f;
    for (int p = b; p < en; p++) { float v = expf(ep[p] - m); ep[p] = v; s += v; }
    const float inv = 1.f / s;
    for (int p = b; p < en; p++) {
        float a = ep[p] * inv;
        ep[p] = a;
        ao[eorig[p]] = a;
    }
}

// fused: ez = edge_attr@W_edge (f16 MFMA) + b_edge; msg = alpha*(z[src]+ez+be);
// edges processed in dst-sorted order -> segmented reduction in LDS, one
// coalesced atomic row per distinct dst per block (~7x fewer atomics).
__global__ __launch_bounds__(256) void aggregate_mfma(
    const int* __restrict__ ssrc, const int* __restrict__ sdst,
    const int* __restrict__ eorig, const float* __restrict__ edge_attr,
    const _Float16* __restrict__ Wefrag, const float* __restrict__ b_edge,
    const _Float16* __restrict__ zb, const float* __restrict__ eperm,
    float* __restrict__ out)
{
    __shared__ float smem[NH * 32 * 65];     // 33280B; front 8KB doubles as f16 A-stage
    __shared__ int srcS[64], dstS[64];
    __shared__ float alphaS[NH][64];
    _Float16* aLDS = (_Float16*)smem;        // 8 chunks x 64 edges x 8 f16 = 8KB

    const int t = threadIdx.x;
    const int p0 = blockIdx.x * 64;
    const int lane = t & 63, h = t >> 6;
    const int q = lane >> 4, l15 = lane & 15;

    if (t < 64) srcS[t] = ssrc[p0 + t];
    else if (t < 128) dstS[t - 64] = sdst[p0 + t - 64];

    // stage edge_attr rows (gathered via eorig) fp32 -> f16 frag-order LDS
    {
        const int m = t >> 2, qq = t & 3;
        const int er = eorig[p0 + m];
        const float4* ap = (const float4*)(edge_attr + (size_t)er * ED_F + qq * 16);
        float4 v4[4];
#pragma unroll
        for (int k = 0; k < 4; k++) v4[k] = ap[k];
        const float* vv = (const float*)v4;
#pragma unroll
        for (int i = 0; i < 2; i++) {
            int c8 = qq * 2 + i;
            f16x8 w;
#pragma unroll
            for (int j = 0; j < 8; j++) w[j] = (_Float16)vv[i * 8 + j];
            *(f16x8*)&aLDS[(c8 * 64 + m) * 8] = w;
        }
    }

    // alpha (already normalized by softmax_kernel), contiguous in sorted order
    alphaS[h][lane] = eperm[(size_t)h * N_EDGES + p0 + lane];

    __syncthreads();

    f16x8 wf[2][4];
#pragma unroll
    for (int kt = 0; kt < 2; kt++)
#pragma unroll
        for (int nt = 0; nt < 4; nt++)
            wf[kt][nt] = *(const f16x8*)&Wefrag[(size_t)(((h * 2 + kt) * 4 + nt) * 64 + lane) * 8];

    f32x4 acc[4][4];
#pragma unroll
    for (int mt = 0; mt < 4; mt++)
#pragma unroll
        for (int nt = 0; nt < 4; nt++) acc[mt][nt] = (f32x4)0.f;

#pragma unroll
    for (int kt = 0; kt < 2; kt++) {
        f16x8 afr[4];
#pragma unroll
        for (int mt = 0; mt < 4; mt++)
            afr[mt] = *(f16x8*)&aLDS[((kt * 4 + q) * 64 + mt * 16 + l15) * 8];
#pragma unroll
        for (int mt = 0; mt < 4; mt++)
#pragma unroll
            for (int nt = 0; nt < 4; nt++)
                acc[mt][nt] = __builtin_amdgcn_mfma_f32_16x16x32_f16(afr[mt], wf[kt][nt], acc[mt][nt], 0, 0, 0);
    }

    __syncthreads();   // all waves done reading aLDS before msgS overwrites it

    const float beL = b_edge[h * OUT_F + lane];
    int cur = dstS[0];
    float accv = 0.f;

#pragma unroll
    for (int half = 0; half < 2; half++) {
        // transpose this half's msg (ez part) into LDS: [h][elh][col], pad 65
#pragma unroll
        for (int mh = 0; mh < 2; mh++) {
            const int mt = half * 2 + mh;
#pragma unroll
            for (int r = 0; r < 4; r++) {
                const int elh = mh * 16 + q * 4 + r;
#pragma unroll
                for (int nt = 0; nt < 4; nt++)
                    smem[(h * 32 + elh) * 65 + nt * 16 + l15] = acc[mt][nt][r];
            }
        }
        __syncthreads();

        // segmented reduce: lane owns column o=lane; run boundary -> one atomic row
#pragma unroll 4
        for (int i = 0; i < 32; i++) {
            const int el = half * 32 + i;
            const int d = dstS[el];
            const float zf = (float)zb[((size_t)h * N_NODES + srcS[el]) * OUT_F + lane];
            const float msg = smem[(h * 32 + i) * 65 + lane];
            const float al = alphaS[h][el];
            if (d != cur) {
                atomicAdd(&out[(size_t)cur * (NH * OUT_F) + h * OUT_F + lane], accv);
                accv = 0.f;
                cur = d;
            }
            accv += al * (msg + beL + zf);
        }
        __syncthreads();   // reduce reads done before next half overwrites msgS
    }
    atomicAdd(&out[(size_t)cur * (NH * OUT_F) + h * OUT_F + lane], accv);
}

extern "C" void kernel_launch(void* const* d_in, const int* in_sizes, int n_in,
                              void* d_out, int out_size, void* d_ws, size_t ws_size,
                              hipStream_t stream) {
    const float* x         = (const float*)d_in[0];
    const int*   edge_index= (const int*)  d_in[1];
    const float* edge_attr = (const float*)d_in[2];
    const float* W_fc      = (const float*)d_in[3];
    const float* b_fc      = (const float*)d_in[4];
    const float* W_att     = (const float*)d_in[5];
    const float* b_att     = (const float*)d_in[6];
    const float* W_edge    = (const float*)d_in[7];
    const float* b_edge    = (const float*)d_in[8];
    const float* W_eatt    = (const float*)d_in[9];
    const float* b_eatt    = (const float*)d_in[10];

    float* out  = (float*)d_out;                          // (N, H*OUT)
    float* ebuf = out + (size_t)N_NODES * NH * OUT_F;     // (H, E): alpha (original order)

    // ws layout (all chunks 16B-aligned by construction)
    _Float16* zb   = (_Float16*)d_ws;                       // NH*N*64 f16 = 25.6MB
    float* a_i     = (float*)(zb + (size_t)NH * N_NODES * OUT_F);
    float* a_j     = a_i + NH * N_NODES;
    float* eperm   = a_j + NH * N_NODES;                    // (H, E) dst-sorted logits->alpha
    float* u       = eperm + (size_t)NH * N_EDGES;          // H*64
    float* c       = u + NH * 64;                           // H
    int* deg       = (int*)(c + NH);
    int* cursor    = deg + N_NODES;
    int* row_ptr   = cursor + N_NODES;                      // N+1 used, N+16 reserved
    int* epos      = row_ptr + (N_NODES + 16);
    int* eorig     = epos + N_EDGES;
    int* ssrc      = eorig + N_EDGES;
    int* sdst      = ssrc + N_EDGES;
    _Float16* Wfcfrag = (_Float16*)(sdst + N_EDGES);        // H*8*4*64*8 halves
    _Float16* Wefrag  = Wfcfrag + NH * 8 * 4 * 64 * 8;      // H*2*4*64*8 halves
    size_t need = (size_t)((char*)(Wefrag + NH * 2 * 4 * 64 * 8) - (char*)d_ws);

    hipMemsetAsync(out, 0, (size_t)N_NODES * NH * OUT_F * sizeof(float), stream);

    if (ws_size < need) {
        // graceful finite-absmax failure instead of OOB fault (canary)
        hipMemsetAsync(ebuf, 0, (size_t)NH * N_EDGES * sizeof(float), stream);
        return;
    }

    hipMemsetAsync(deg, 0, N_NODES * sizeof(int), stream);

    prep_kernel<<<41, 256, 0, stream>>>(W_att, b_att, W_eatt, b_eatt, W_fc, W_edge,
                                        u, c, Wfcfrag, Wefrag);

    hist_kernel<<<(N_EDGES + 255) / 256, 256, 0, stream>>>(edge_index, deg);
    scan_kernel<<<1, 256, 0, stream>>>(deg, row_ptr, cursor);
    scatter_kernel<<<(N_EDGES + 255) / 256, 256, 0, stream>>>(edge_index, cursor,
                                                              epos, eorig, ssrc, sdst);

    z_gemm<<<(N_NODES + 63) / 64, 256, 0, stream>>>(x, Wfcfrag, b_fc, zb);

    a_ij_kernel<<<N_NODES / 16, 256, 0, stream>>>(zb, W_att, a_i, a_j);

    logits_kernel<<<N_EDGES / 4, 256, 0, stream>>>(edge_index, edge_attr, u, c,
                                                   a_i, a_j, epos, eperm);

    dim3 sg((N_NODES + 255) / 256, NH);
    softmax_kernel<<<sg, 256, 0, stream>>>(row_ptr, eorig, eperm, ebuf);

    aggregate_mfma<<<N_EDGES / 64, 256, 0, stream>>>(ssrc, sdst, eorig, edge_attr,
                                                     Wefrag, b_edge, zb, eperm, out);
}

// Round 2
// 634.598 us; speedup vs baseline: 1.4393x; 1.2867x over previous
//
#include <hip/hip_runtime.h>
#include <math.h>

#define N_NODES 50000
#define N_EDGES 400000
#define IN_F 256
#define OUT_F 64
#define ED_F 64
#define NH 4

using f16x8 = __attribute__((ext_vector_type(8))) _Float16;
using f32x4 = __attribute__((ext_vector_type(4))) float;

// block 0: u[h][f] = sum_g W_eatt[h][f][g]*We[h][g]; c[h] = b_att[h] + b_eatt[h].We[h]
// blocks 1..32: Wfcfrag (f16, MFMA b-frag order), blocks 33..40: Wefrag
__global__ __launch_bounds__(256) void prep_kernel(
    const float* __restrict__ W_att, const float* __restrict__ b_att,
    const float* __restrict__ W_eatt, const float* __restrict__ b_eatt,
    const float* __restrict__ W_fc, const float* __restrict__ W_edge,
    float* __restrict__ u, float* __restrict__ c,
    _Float16* __restrict__ Wfcfrag, _Float16* __restrict__ Wefrag)
{
    const int b = blockIdx.x, t = threadIdx.x;
    if (b == 0) {
        int h = t >> 6, f = t & 63;
        const float* We = W_att + h * (2 * OUT_F + ED_F) + 2 * OUT_F;
        float s = 0.f;
        for (int g = 0; g < ED_F; g++) s += W_eatt[(h * ED_F + f) * ED_F + g] * We[g];
        u[t] = s;
        if (f == 0) {
            float cc = b_att[h];
            for (int g = 0; g < ED_F; g++) cc += b_eatt[h * ED_F + g] * We[g];
            c[h] = cc;
        }
    } else if (b <= 32) {
        // b_frag[lane][j] = B[k=quad*8+j][n=lane&15], B = W_fc[h] (256x64)
        int idx = b - 1;
        int h = idx >> 3, kt = idx & 7;
        int lane = t & 63, nt = t >> 6;
        int q = lane >> 4, l15 = lane & 15;
        f16x8 w;
#pragma unroll
        for (int j = 0; j < 8; j++) {
            int k = kt * 32 + q * 8 + j;
            int o = nt * 16 + l15;
            w[j] = (_Float16)W_fc[((size_t)h * IN_F + k) * OUT_F + o];
        }
        *(f16x8*)&Wfcfrag[(size_t)(((h * 8 + kt) * 4 + nt) * 64 + lane) * 8] = w;
    } else {
        int idx = b - 33;
        int h = idx >> 1, kt = idx & 1;
        int lane = t & 63, nt = t >> 6;
        int q = lane >> 4, l15 = lane & 15;
        f16x8 w;
#pragma unroll
        for (int j = 0; j < 8; j++) {
            int k = kt * 32 + q * 8 + j;
            int o = nt * 16 + l15;
            w[j] = (_Float16)W_edge[((size_t)h * ED_F + k) * OUT_F + o];
        }
        *(f16x8*)&Wefrag[(size_t)(((h * 2 + kt) * 4 + nt) * 64 + lane) * 8] = w;
    }
}

// z[h][n][o] = x@W_fc + b_fc, f16 MFMA 16x16x32. Block: 64 nodes, 4 waves = 4 heads.
// Fused epilogue: a_i[h][n] = z.Wi, a_j[h][n] = z.Wj (computed from fp32 acc).
__global__ __launch_bounds__(256) void z_gemm(
    const float* __restrict__ x, const _Float16* __restrict__ Wfcfrag,
    const float* __restrict__ b_fc, const float* __restrict__ W_att,
    _Float16* __restrict__ zb, float* __restrict__ a_i, float* __restrict__ a_j)
{
    __shared__ _Float16 aLDS[32 * 64 * 8];   // 32 chunks(kt,quad) x 64 nodes x 8 f16 = 32KB
    const int t = threadIdx.x;
    const int n0 = blockIdx.x * 64;
    const int lane = t & 63, h = t >> 6;
    const int q = lane >> 4, l15 = lane & 15;

    // stage x tile (64 nodes x 256 k) fp32 -> f16 frag-order LDS
    {
        const int m = t >> 2, qq = t & 3;
        const int n = n0 + m;
#pragma unroll
        for (int p = 0; p < 4; p++) {
            float4 v4[4];
            if (n < N_NODES) {
                const float4* xp = (const float4*)(x + (size_t)n * IN_F + p * 64 + qq * 16);
#pragma unroll
                for (int k = 0; k < 4; k++) v4[k] = xp[k];
            } else {
#pragma unroll
                for (int k = 0; k < 4; k++) v4[k] = make_float4(0.f, 0.f, 0.f, 0.f);
            }
            const float* vv = (const float*)v4;
#pragma unroll
            for (int i = 0; i < 2; i++) {
                int c8 = p * 8 + qq * 2 + i;
                f16x8 w;
#pragma unroll
                for (int j = 0; j < 8; j++) w[j] = (_Float16)vv[i * 8 + j];
                *(f16x8*)&aLDS[(c8 * 64 + m) * 8] = w;
            }
        }
    }
    __syncthreads();

    f32x4 acc[4][4];
#pragma unroll
    for (int mt = 0; mt < 4; mt++)
#pragma unroll
        for (int nt = 0; nt < 4; nt++) acc[mt][nt] = (f32x4)0.f;

    for (int kt = 0; kt < 8; kt++) {
        f16x8 bfr[4];
#pragma unroll
        for (int nt = 0; nt < 4; nt++)
            bfr[nt] = *(const f16x8*)&Wfcfrag[(size_t)(((h * 8 + kt) * 4 + nt) * 64 + lane) * 8];
        f16x8 afr[4];
#pragma unroll
        for (int mt = 0; mt < 4; mt++)
            afr[mt] = *(f16x8*)&aLDS[((kt * 4 + q) * 64 + mt * 16 + l15) * 8];
#pragma unroll
        for (int mt = 0; mt < 4; mt++)
#pragma unroll
            for (int nt = 0; nt < 4; nt++)
                acc[mt][nt] = __builtin_amdgcn_mfma_f32_16x16x32_f16(afr[mt], bfr[nt], acc[mt][nt], 0, 0, 0);
    }

    float bfc[4], wiv[4], wjv[4];
#pragma unroll
    for (int nt = 0; nt < 4; nt++) {
        bfc[nt] = b_fc[h * OUT_F + nt * 16 + l15];
        wiv[nt] = W_att[h * 192 + nt * 16 + l15];
        wjv[nt] = W_att[h * 192 + 64 + nt * 16 + l15];
    }

    // C/D layout: col = lane&15, row = quad*4 + reg
#pragma unroll
    for (int mt = 0; mt < 4; mt++) {
#pragma unroll
        for (int r = 0; r < 4; r++) {
            const int node = n0 + mt * 16 + q * 4 + r;
            float zv[4];
            float pi = 0.f, pj = 0.f;
#pragma unroll
            for (int nt = 0; nt < 4; nt++) {
                zv[nt] = acc[mt][nt][r] + bfc[nt];
                pi += zv[nt] * wiv[nt];
                pj += zv[nt] * wjv[nt];
            }
            // reduce over the 16 l15 lanes (same q group -> same node)
#pragma unroll
            for (int m = 8; m; m >>= 1) {
                pi += __shfl_xor(pi, m, 64);
                pj += __shfl_xor(pj, m, 64);
            }
            if (node < N_NODES) {
                _Float16* zrow = zb + ((size_t)h * N_NODES + node) * OUT_F;
#pragma unroll
                for (int nt = 0; nt < 4; nt++)
                    zrow[nt * 16 + l15] = (_Float16)zv[nt];
                if (l15 == 0) {
                    a_i[h * N_NODES + node] = pi;
                    a_j[h * N_NODES + node] = pj;
                }
            }
        }
    }
}

// --- counting-sort by dst -------------------------------------------------

__global__ __launch_bounds__(256) void hist_kernel(
    const int* __restrict__ edge_index, int* __restrict__ deg)
{
    const int e = blockIdx.x * 256 + threadIdx.x;
    if (e < N_EDGES) atomicAdd(&deg[edge_index[N_EDGES + e]], 1);
}

// single-block exclusive scan over deg[0..N) -> row_ptr[0..N], cursor copy
__global__ __launch_bounds__(256) void scan_kernel(
    const int* __restrict__ deg, int* __restrict__ row_ptr, int* __restrict__ cursor)
{
    __shared__ int wsum[4];
    const int t = threadIdx.x, lane = t & 63, w = t >> 6;
    int running = 0;
    const int nchunk = (N_NODES + 255) / 256;
    for (int ck = 0; ck < nchunk; ck++) {
        int idx = ck * 256 + t;
        int v = (idx < N_NODES) ? deg[idx] : 0;
        int x = v;
#pragma unroll
        for (int off = 1; off < 64; off <<= 1) {
            int y = __shfl_up(x, off, 64);
            if (lane >= off) x += y;
        }
        if (lane == 63) wsum[w] = x;
        __syncthreads();
        int woff = 0;
#pragma unroll
        for (int i = 0; i < 4; i++) if (i < w) woff += wsum[i];
        int tot = wsum[0] + wsum[1] + wsum[2] + wsum[3];
        int excl = running + woff + x - v;
        if (idx < N_NODES) { row_ptr[idx] = excl; cursor[idx] = excl; }
        running += tot;
        __syncthreads();
    }
    if (t == 0) row_ptr[N_NODES] = running;
}

__global__ __launch_bounds__(256) void scatter_kernel(
    const int* __restrict__ edge_index, int* __restrict__ cursor,
    int* __restrict__ eorig, int* __restrict__ ssrc, int* __restrict__ sdst)
{
    const int e = blockIdx.x * 256 + threadIdx.x;
    if (e >= N_EDGES) return;
    const int d = edge_index[N_EDGES + e];
    const int pos = atomicAdd(&cursor[d], 1);
    eorig[pos] = e;
    ssrc[pos] = edge_index[e];
    sdst[pos] = d;
}

// thread per sorted position p: all 4 head logits in registers, no shuffles.
// edge_attr row gathered via eorig (256B rows -> full line utilization);
// eperm writes coalesced; a_i gathers are run-sequential (dst-sorted).
__global__ __launch_bounds__(256) void logits_kernel(
    const int* __restrict__ ssrc, const int* __restrict__ sdst,
    const int* __restrict__ eorig, const float* __restrict__ edge_attr,
    const float* __restrict__ u, const float* __restrict__ c,
    const float* __restrict__ a_i, const float* __restrict__ a_j,
    float* __restrict__ eperm)
{
    __shared__ float uS[NH * ED_F];
    __shared__ float cS[NH];
    const int t = threadIdx.x;
    uS[t] = u[t];
    if (t < NH) cS[t] = c[t];
    __syncthreads();

    const int p = blockIdx.x * 256 + t;
    if (p >= N_EDGES) return;
    const int e = eorig[p];
    const int src = ssrc[p];
    const int dst = sdst[p];
    const float4* ap = (const float4*)(edge_attr + (size_t)e * ED_F);

    float acc[NH] = {0.f, 0.f, 0.f, 0.f};
#pragma unroll
    for (int j = 0; j < 16; j++) {
        const float4 v = ap[j];
#pragma unroll
        for (int h = 0; h < NH; h++) {
            const float4 uv = *(const float4*)&uS[h * ED_F + j * 4];
            acc[h] += v.x * uv.x + v.y * uv.y + v.z * uv.z + v.w * uv.w;
        }
    }
#pragma unroll
    for (int h = 0; h < NH; h++) {
        float a = acc[h] + a_i[h * N_NODES + dst] + a_j[h * N_NODES + src] + cS[h];
        float ev = a > 0.f ? a : 0.2f * a;
        eperm[(size_t)h * N_EDGES + p] = ev;
    }
}

// per (node, head): serial softmax over the node's contiguous sorted run.
// Converts eperm logits -> alpha in place; scatters alpha to original order.
__global__ __launch_bounds__(256) void softmax_kernel(
    const int* __restrict__ row_ptr, const int* __restrict__ eorig,
    float* __restrict__ eperm, float* __restrict__ alpha_out)
{
    const int n = blockIdx.x * 256 + threadIdx.x;
    if (n >= N_NODES) return;
    const int b = row_ptr[n], en = row_ptr[n + 1];
    if (b >= en) return;
    const int h = blockIdx.y;
    float* ep = eperm + (size_t)h * N_EDGES;
    float* ao = alpha_out + (size_t)h * N_EDGES;
    float m = -INFINITY;
    for (int p = b; p < en; p++) m = fmaxf(m, ep[p]);
    float s = 0.f;
    for (int p = b; p < en; p++) { float v = expf(ep[p] - m); ep[p] = v; s += v; }
    const float inv = 1.f / s;
    for (int p = b; p < en; p++) {
        float a = ep[p] * inv;
        ep[p] = a;
        ao[eorig[p]] = a;
    }
}

// fused: ez = edge_attr@W_edge (f16 MFMA) + b_edge; msg = alpha*(z[src]+ez+be);
// edges processed in dst-sorted order -> segmented reduction in LDS, one
// coalesced atomic row per distinct dst per block (~7x fewer atomics).
__global__ __launch_bounds__(256) void aggregate_mfma(
    const int* __restrict__ ssrc, const int* __restrict__ sdst,
    const int* __restrict__ eorig, const float* __restrict__ edge_attr,
    const _Float16* __restrict__ Wefrag, const float* __restrict__ b_edge,
    const _Float16* __restrict__ zb, const float* __restrict__ eperm,
    float* __restrict__ out)
{
    __shared__ float smem[NH * 32 * 65];     // 33280B; front 8KB doubles as f16 A-stage
    __shared__ int srcS[64], dstS[64];
    __shared__ float alphaS[NH][64];
    _Float16* aLDS = (_Float16*)smem;        // 8 chunks x 64 edges x 8 f16 = 8KB

    const int t = threadIdx.x;
    const int p0 = blockIdx.x * 64;
    const int lane = t & 63, h = t >> 6;
    const int q = lane >> 4, l15 = lane & 15;

    if (t < 64) srcS[t] = ssrc[p0 + t];
    else if (t < 128) dstS[t - 64] = sdst[p0 + t - 64];

    // stage edge_attr rows (gathered via eorig) fp32 -> f16 frag-order LDS
    {
        const int m = t >> 2, qq = t & 3;
        const int er = eorig[p0 + m];
        const float4* ap = (const float4*)(edge_attr + (size_t)er * ED_F + qq * 16);
        float4 v4[4];
#pragma unroll
        for (int k = 0; k < 4; k++) v4[k] = ap[k];
        const float* vv = (const float*)v4;
#pragma unroll
        for (int i = 0; i < 2; i++) {
            int c8 = qq * 2 + i;
            f16x8 w;
#pragma unroll
            for (int j = 0; j < 8; j++) w[j] = (_Float16)vv[i * 8 + j];
            *(f16x8*)&aLDS[(c8 * 64 + m) * 8] = w;
        }
    }

    // alpha (already normalized by softmax_kernel), contiguous in sorted order
    alphaS[h][lane] = eperm[(size_t)h * N_EDGES + p0 + lane];

    __syncthreads();

    f16x8 wf[2][4];
#pragma unroll
    for (int kt = 0; kt < 2; kt++)
#pragma unroll
        for (int nt = 0; nt < 4; nt++)
            wf[kt][nt] = *(const f16x8*)&Wefrag[(size_t)(((h * 2 + kt) * 4 + nt) * 64 + lane) * 8];

    f32x4 acc[4][4];
#pragma unroll
    for (int mt = 0; mt < 4; mt++)
#pragma unroll
        for (int nt = 0; nt < 4; nt++) acc[mt][nt] = (f32x4)0.f;

#pragma unroll
    for (int kt = 0; kt < 2; kt++) {
        f16x8 afr[4];
#pragma unroll
        for (int mt = 0; mt < 4; mt++)
            afr[mt] = *(f16x8*)&aLDS[((kt * 4 + q) * 64 + mt * 16 + l15) * 8];
#pragma unroll
        for (int mt = 0; mt < 4; mt++)
#pragma unroll
            for (int nt = 0; nt < 4; nt++)
                acc[mt][nt] = __builtin_amdgcn_mfma_f32_16x16x32_f16(afr[mt], wf[kt][nt], acc[mt][nt], 0, 0, 0);
    }

    __syncthreads();   // all waves done reading aLDS before msgS overwrites it

    const float beL = b_edge[h * OUT_F + lane];
    int cur = dstS[0];
    float accv = 0.f;

#pragma unroll
    for (int half = 0; half < 2; half++) {
        // transpose this half's msg (ez part) into LDS: [h][elh][col], pad 65
#pragma unroll
        for (int mh = 0; mh < 2; mh++) {
            const int mt = half * 2 + mh;
#pragma unroll
            for (int r = 0; r < 4; r++) {
                const int elh = mh * 16 + q * 4 + r;
#pragma unroll
                for (int nt = 0; nt < 4; nt++)
                    smem[(h * 32 + elh) * 65 + nt * 16 + l15] = acc[mt][nt][r];
            }
        }
        __syncthreads();

        // segmented reduce: lane owns column o=lane; run boundary -> one atomic row
#pragma unroll 4
        for (int i = 0; i < 32; i++) {
            const int el = half * 32 + i;
            const int d = dstS[el];
            const float zf = (float)zb[((size_t)h * N_NODES + srcS[el]) * OUT_F + lane];
            const float msg = smem[(h * 32 + i) * 65 + lane];
            const float al = alphaS[h][el];
            if (d != cur) {
                atomicAdd(&out[(size_t)cur * (NH * OUT_F) + h * OUT_F + lane], accv);
                accv = 0.f;
                cur = d;
            }
            accv += al * (msg + beL + zf);
        }
        __syncthreads();   // reduce reads done before next half overwrites msgS
    }
    atomicAdd(&out[(size_t)cur * (NH * OUT_F) + h * OUT_F + lane], accv);
}

extern "C" void kernel_launch(void* const* d_in, const int* in_sizes, int n_in,
                              void* d_out, int out_size, void* d_ws, size_t ws_size,
                              hipStream_t stream) {
    const float* x         = (const float*)d_in[0];
    const int*   edge_index= (const int*)  d_in[1];
    const float* edge_attr = (const float*)d_in[2];
    const float* W_fc      = (const float*)d_in[3];
    const float* b_fc      = (const float*)d_in[4];
    const float* W_att     = (const float*)d_in[5];
    const float* b_att     = (const float*)d_in[6];
    const float* W_edge    = (const float*)d_in[7];
    const float* b_edge    = (const float*)d_in[8];
    const float* W_eatt    = (const float*)d_in[9];
    const float* b_eatt    = (const float*)d_in[10];

    float* out  = (float*)d_out;                          // (N, H*OUT)
    float* ebuf = out + (size_t)N_NODES * NH * OUT_F;     // (H, E): alpha (original order)

    // ws layout (all chunks 16B-aligned by construction)
    _Float16* zb   = (_Float16*)d_ws;                       // NH*N*64 f16 = 25.6MB
    float* a_i     = (float*)(zb + (size_t)NH * N_NODES * OUT_F);
    float* a_j     = a_i + NH * N_NODES;
    float* eperm   = a_j + NH * N_NODES;                    // (H, E) dst-sorted logits->alpha
    float* u       = eperm + (size_t)NH * N_EDGES;          // H*64
    float* c       = u + NH * 64;                           // H
    int* deg       = (int*)(c + NH);
    int* cursor    = deg + N_NODES;
    int* row_ptr   = cursor + N_NODES;                      // N+1 used, N+16 reserved
    int* eorig     = row_ptr + (N_NODES + 16);
    int* ssrc      = eorig + N_EDGES;
    int* sdst      = ssrc + N_EDGES;
    _Float16* Wfcfrag = (_Float16*)(sdst + N_EDGES);        // H*8*4*64*8 halves
    _Float16* Wefrag  = Wfcfrag + NH * 8 * 4 * 64 * 8;      // H*2*4*64*8 halves
    size_t need = (size_t)((char*)(Wefrag + NH * 2 * 4 * 64 * 8) - (char*)d_ws);

    hipMemsetAsync(out, 0, (size_t)N_NODES * NH * OUT_F * sizeof(float), stream);

    if (ws_size < need) {
        // graceful finite-absmax failure instead of OOB fault (canary)
        hipMemsetAsync(ebuf, 0, (size_t)NH * N_EDGES * sizeof(float), stream);
        return;
    }

    hipMemsetAsync(deg, 0, N_NODES * sizeof(int), stream);

    prep_kernel<<<41, 256, 0, stream>>>(W_att, b_att, W_eatt, b_eatt, W_fc, W_edge,
                                        u, c, Wfcfrag, Wefrag);

    hist_kernel<<<(N_EDGES + 255) / 256, 256, 0, stream>>>(edge_index, deg);
    scan_kernel<<<1, 256, 0, stream>>>(deg, row_ptr, cursor);
    scatter_kernel<<<(N_EDGES + 255) / 256, 256, 0, stream>>>(edge_index, cursor,
                                                              eorig, ssrc, sdst);

    z_gemm<<<(N_NODES + 63) / 64, 256, 0, stream>>>(x, Wfcfrag, b_fc, W_att,
                                                    zb, a_i, a_j);

    logits_kernel<<<(N_EDGES + 255) / 256, 256, 0, stream>>>(ssrc, sdst, eorig, edge_attr,
                                                             u, c, a_i, a_j, eperm);

    dim3 sg((N_NODES + 255) / 256, NH);
    softmax_kernel<<<sg, 256, 0, stream>>>(row_ptr, eorig, eperm, ebuf);

    aggregate_mfma<<<N_EDGES / 64, 256, 0, stream>>>(ssrc, sdst, eorig, edge_attr,
                                                     Wefrag, b_edge, zb, eperm, out);
}

// Round 3
// 441.752 us; speedup vs baseline: 2.0676x; 1.4366x over previous
//
#include <hip/hip_runtime.h>
#include <math.h>

#define N_NODES 50000
#define N_EDGES 400000
#define IN_F 256
#define OUT_F 64
#define ED_F 64
#define NH 4
#define SCAN_NB ((N_NODES + 255) / 256)

using f16x8 = __attribute__((ext_vector_type(8))) _Float16;
using f32x4 = __attribute__((ext_vector_type(4))) float;

// block 0: u[h][f] = sum_g W_eatt[h][f][g]*We[h][g]; c[h] = b_att[h] + b_eatt[h].We[h]
// blocks 1..32: Wfcfrag (f16, MFMA b-frag order), blocks 33..40: Wefrag
__global__ __launch_bounds__(256) void prep_kernel(
    const float* __restrict__ W_att, const float* __restrict__ b_att,
    const float* __restrict__ W_eatt, const float* __restrict__ b_eatt,
    const float* __restrict__ W_fc, const float* __restrict__ W_edge,
    float* __restrict__ u, float* __restrict__ c,
    _Float16* __restrict__ Wfcfrag, _Float16* __restrict__ Wefrag)
{
    const int b = blockIdx.x, t = threadIdx.x;
    if (b == 0) {
        int h = t >> 6, f = t & 63;
        const float* We = W_att + h * (2 * OUT_F + ED_F) + 2 * OUT_F;
        float s = 0.f;
        for (int g = 0; g < ED_F; g++) s += W_eatt[(h * ED_F + f) * ED_F + g] * We[g];
        u[t] = s;
        if (f == 0) {
            float cc = b_att[h];
            for (int g = 0; g < ED_F; g++) cc += b_eatt[h * ED_F + g] * We[g];
            c[h] = cc;
        }
    } else if (b <= 32) {
        // b_frag[lane][j] = B[k=quad*8+j][n=lane&15], B = W_fc[h] (256x64)
        int idx = b - 1;
        int h = idx >> 3, kt = idx & 7;
        int lane = t & 63, nt = t >> 6;
        int q = lane >> 4, l15 = lane & 15;
        f16x8 w;
#pragma unroll
        for (int j = 0; j < 8; j++) {
            int k = kt * 32 + q * 8 + j;
            int o = nt * 16 + l15;
            w[j] = (_Float16)W_fc[((size_t)h * IN_F + k) * OUT_F + o];
        }
        *(f16x8*)&Wfcfrag[(size_t)(((h * 8 + kt) * 4 + nt) * 64 + lane) * 8] = w;
    } else {
        int idx = b - 33;
        int h = idx >> 1, kt = idx & 1;
        int lane = t & 63, nt = t >> 6;
        int q = lane >> 4, l15 = lane & 15;
        f16x8 w;
#pragma unroll
        for (int j = 0; j < 8; j++) {
            int k = kt * 32 + q * 8 + j;
            int o = nt * 16 + l15;
            w[j] = (_Float16)W_edge[((size_t)h * ED_F + k) * OUT_F + o];
        }
        *(f16x8*)&Wefrag[(size_t)(((h * 2 + kt) * 4 + nt) * 64 + lane) * 8] = w;
    }
}

// z[h][n][o] = x@W_fc + b_fc, f16 MFMA 16x16x32. Block: 64 nodes, 4 waves = 4 heads.
// Fused epilogue: a_i[h][n] = z.Wi, a_j[h][n] = z.Wj (computed from fp32 acc).
__global__ __launch_bounds__(256) void z_gemm(
    const float* __restrict__ x, const _Float16* __restrict__ Wfcfrag,
    const float* __restrict__ b_fc, const float* __restrict__ W_att,
    _Float16* __restrict__ zb, float* __restrict__ a_i, float* __restrict__ a_j)
{
    __shared__ _Float16 aLDS[32 * 64 * 8];   // 32 chunks(kt,quad) x 64 nodes x 8 f16 = 32KB
    const int t = threadIdx.x;
    const int n0 = blockIdx.x * 64;
    const int lane = t & 63, h = t >> 6;
    const int q = lane >> 4, l15 = lane & 15;

    // stage x tile (64 nodes x 256 k) fp32 -> f16 frag-order LDS
    {
        const int m = t >> 2, qq = t & 3;
        const int n = n0 + m;
#pragma unroll
        for (int p = 0; p < 4; p++) {
            float4 v4[4];
            if (n < N_NODES) {
                const float4* xp = (const float4*)(x + (size_t)n * IN_F + p * 64 + qq * 16);
#pragma unroll
                for (int k = 0; k < 4; k++) v4[k] = xp[k];
            } else {
#pragma unroll
                for (int k = 0; k < 4; k++) v4[k] = make_float4(0.f, 0.f, 0.f, 0.f);
            }
            const float* vv = (const float*)v4;
#pragma unroll
            for (int i = 0; i < 2; i++) {
                int c8 = p * 8 + qq * 2 + i;
                f16x8 w;
#pragma unroll
                for (int j = 0; j < 8; j++) w[j] = (_Float16)vv[i * 8 + j];
                *(f16x8*)&aLDS[(c8 * 64 + m) * 8] = w;
            }
        }
    }
    __syncthreads();

    f32x4 acc[4][4];
#pragma unroll
    for (int mt = 0; mt < 4; mt++)
#pragma unroll
        for (int nt = 0; nt < 4; nt++) acc[mt][nt] = (f32x4)0.f;

    for (int kt = 0; kt < 8; kt++) {
        f16x8 bfr[4];
#pragma unroll
        for (int nt = 0; nt < 4; nt++)
            bfr[nt] = *(const f16x8*)&Wfcfrag[(size_t)(((h * 8 + kt) * 4 + nt) * 64 + lane) * 8];
        f16x8 afr[4];
#pragma unroll
        for (int mt = 0; mt < 4; mt++)
            afr[mt] = *(f16x8*)&aLDS[((kt * 4 + q) * 64 + mt * 16 + l15) * 8];
#pragma unroll
        for (int mt = 0; mt < 4; mt++)
#pragma unroll
            for (int nt = 0; nt < 4; nt++)
                acc[mt][nt] = __builtin_amdgcn_mfma_f32_16x16x32_f16(afr[mt], bfr[nt], acc[mt][nt], 0, 0, 0);
    }

    float bfc[4], wiv[4], wjv[4];
#pragma unroll
    for (int nt = 0; nt < 4; nt++) {
        bfc[nt] = b_fc[h * OUT_F + nt * 16 + l15];
        wiv[nt] = W_att[h * 192 + nt * 16 + l15];
        wjv[nt] = W_att[h * 192 + 64 + nt * 16 + l15];
    }

    // C/D layout: col = lane&15, row = quad*4 + reg
#pragma unroll
    for (int mt = 0; mt < 4; mt++) {
#pragma unroll
        for (int r = 0; r < 4; r++) {
            const int node = n0 + mt * 16 + q * 4 + r;
            float zv[4];
            float pi = 0.f, pj = 0.f;
#pragma unroll
            for (int nt = 0; nt < 4; nt++) {
                zv[nt] = acc[mt][nt][r] + bfc[nt];
                pi += zv[nt] * wiv[nt];
                pj += zv[nt] * wjv[nt];
            }
            // reduce over the 16 l15 lanes (same q group -> same node)
#pragma unroll
            for (int m = 8; m; m >>= 1) {
                pi += __shfl_xor(pi, m, 64);
                pj += __shfl_xor(pj, m, 64);
            }
            if (node < N_NODES) {
                _Float16* zrow = zb + ((size_t)h * N_NODES + node) * OUT_F;
#pragma unroll
                for (int nt = 0; nt < 4; nt++)
                    zrow[nt * 16 + l15] = (_Float16)zv[nt];
                if (l15 == 0) {
                    a_i[h * N_NODES + node] = pi;
                    a_j[h * N_NODES + node] = pj;
                }
            }
        }
    }
}

// --- counting-sort by dst -------------------------------------------------

__global__ __launch_bounds__(256) void hist_kernel(
    const int* __restrict__ edge_index, int* __restrict__ deg)
{
    const int e = blockIdx.x * 256 + threadIdx.x;
    if (e < N_EDGES) atomicAdd(&deg[edge_index[N_EDGES + e]], 1);
}

// hierarchical scan phase 1: per-block exclusive scan + block totals
__global__ __launch_bounds__(256) void scan1_kernel(
    const int* __restrict__ deg, int* __restrict__ row_ptr, int* __restrict__ bsum)
{
    __shared__ int wsum[4];
    const int t = threadIdx.x, lane = t & 63, w = t >> 6;
    const int idx = blockIdx.x * 256 + t;
    int v = (idx < N_NODES) ? deg[idx] : 0;
    int x = v;
#pragma unroll
    for (int off = 1; off < 64; off <<= 1) {
        int y = __shfl_up(x, off, 64);
        if (lane >= off) x += y;
    }
    if (lane == 63) wsum[w] = x;
    __syncthreads();
    int woff = 0;
#pragma unroll
    for (int i = 0; i < 4; i++) if (i < w) woff += wsum[i];
    if (idx < N_NODES) row_ptr[idx] = woff + x - v;
    if (t == 255) bsum[blockIdx.x] = woff + x;
}

// phase 2: single block scans the <=256 block totals in place (exclusive)
__global__ __launch_bounds__(256) void scan2_kernel(int* __restrict__ bsum)
{
    __shared__ int wsum[4];
    const int t = threadIdx.x, lane = t & 63, w = t >> 6;
    int v = (t < SCAN_NB) ? bsum[t] : 0;
    int x = v;
#pragma unroll
    for (int off = 1; off < 64; off <<= 1) {
        int y = __shfl_up(x, off, 64);
        if (lane >= off) x += y;
    }
    if (lane == 63) wsum[w] = x;
    __syncthreads();
    int woff = 0;
#pragma unroll
    for (int i = 0; i < 4; i++) if (i < w) woff += wsum[i];
    __syncthreads();
    if (t < SCAN_NB) bsum[t] = woff + x - v;
}

// phase 3: add block offsets, produce cursor copy and row_ptr[N]
__global__ __launch_bounds__(256) void scan3_kernel(
    const int* __restrict__ bsum, int* __restrict__ row_ptr, int* __restrict__ cursor)
{
    const int idx = blockIdx.x * 256 + threadIdx.x;
    if (idx < N_NODES) {
        int rp = row_ptr[idx] + bsum[blockIdx.x];
        row_ptr[idx] = rp;
        cursor[idx] = rp;
    } else if (idx == N_NODES) {
        row_ptr[N_NODES] = N_EDGES;
    }
}

__global__ __launch_bounds__(256) void scatter_kernel(
    const int* __restrict__ edge_index, int* __restrict__ cursor,
    int* __restrict__ eorig, int* __restrict__ ssrc, int* __restrict__ sdst)
{
    const int e = blockIdx.x * 256 + threadIdx.x;
    if (e >= N_EDGES) return;
    const int d = edge_index[N_EDGES + e];
    const int pos = atomicAdd(&cursor[d], 1);
    eorig[pos] = e;
    ssrc[pos] = edge_index[e];
    sdst[pos] = d;
}

// thread per sorted position p: all 4 head logits in registers, no shuffles.
__global__ __launch_bounds__(256) void logits_kernel(
    const int* __restrict__ ssrc, const int* __restrict__ sdst,
    const int* __restrict__ eorig, const float* __restrict__ edge_attr,
    const float* __restrict__ u, const float* __restrict__ c,
    const float* __restrict__ a_i, const float* __restrict__ a_j,
    float* __restrict__ eperm)
{
    __shared__ float uS[NH * ED_F];
    __shared__ float cS[NH];
    const int t = threadIdx.x;
    uS[t] = u[t];
    if (t < NH) cS[t] = c[t];
    __syncthreads();

    const int p = blockIdx.x * 256 + t;
    if (p >= N_EDGES) return;
    const int e = eorig[p];
    const int src = ssrc[p];
    const int dst = sdst[p];
    const float4* ap = (const float4*)(edge_attr + (size_t)e * ED_F);

    float acc[NH] = {0.f, 0.f, 0.f, 0.f};
#pragma unroll
    for (int j = 0; j < 16; j++) {
        const float4 v = ap[j];
#pragma unroll
        for (int h = 0; h < NH; h++) {
            const float4 uv = *(const float4*)&uS[h * ED_F + j * 4];
            acc[h] += v.x * uv.x + v.y * uv.y + v.z * uv.z + v.w * uv.w;
        }
    }
#pragma unroll
    for (int h = 0; h < NH; h++) {
        float a = acc[h] + a_i[h * N_NODES + dst] + a_j[h * N_NODES + src] + cS[h];
        float ev = a > 0.f ? a : 0.2f * a;
        eperm[(size_t)h * N_EDGES + p] = ev;
    }
}

// per (node, head): serial softmax over the node's contiguous sorted run.
__global__ __launch_bounds__(256) void softmax_kernel(
    const int* __restrict__ row_ptr, const int* __restrict__ eorig,
    float* __restrict__ eperm, float* __restrict__ alpha_out)
{
    const int n = blockIdx.x * 256 + threadIdx.x;
    if (n >= N_NODES) return;
    const int b = row_ptr[n], en = row_ptr[n + 1];
    if (b >= en) return;
    const int h = blockIdx.y;
    float* ep = eperm + (size_t)h * N_EDGES;
    float* ao = alpha_out + (size_t)h * N_EDGES;
    float m = -INFINITY;
    for (int p = b; p < en; p++) m = fmaxf(m, ep[p]);
    float s = 0.f;
    for (int p = b; p < en; p++) { float v = expf(ep[p] - m); ep[p] = v; s += v; }
    const float inv = 1.f / s;
    for (int p = b; p < en; p++) {
        float a = ep[p] * inv;
        ep[p] = a;
        ao[eorig[p]] = a;
    }
}

// fused: ez = edge_attr@W_edge (f16 MFMA) + b_edge; msg = alpha*(z[src]+ez+be);
// dst-sorted segmented reduction; pad-66 transpose (2-way banks = free);
// zb gather prefetched 32-deep into registers per half.
__global__ __launch_bounds__(256) void aggregate_mfma(
    const int* __restrict__ ssrc, const int* __restrict__ sdst,
    const int* __restrict__ eorig, const float* __restrict__ edge_attr,
    const _Float16* __restrict__ Wefrag, const float* __restrict__ b_edge,
    const _Float16* __restrict__ zb, const float* __restrict__ eperm,
    float* __restrict__ out)
{
    __shared__ float smem[NH * 32 * 66];     // 33792B; front 8KB doubles as f16 A-stage
    __shared__ int srcS[64], dstS[64];
    __shared__ float alphaS[NH][64];
    _Float16* aLDS = (_Float16*)smem;        // 8 chunks x 64 edges x 8 f16 = 8KB

    const int t = threadIdx.x;
    const int p0 = blockIdx.x * 64;
    const int lane = t & 63, h = t >> 6;
    const int q = lane >> 4, l15 = lane & 15;

    if (t < 64) srcS[t] = ssrc[p0 + t];
    else if (t < 128) dstS[t - 64] = sdst[p0 + t - 64];

    // stage edge_attr rows (gathered via eorig) fp32 -> f16 frag-order LDS
    {
        const int m = t >> 2, qq = t & 3;
        const int er = eorig[p0 + m];
        const float4* ap = (const float4*)(edge_attr + (size_t)er * ED_F + qq * 16);
        float4 v4[4];
#pragma unroll
        for (int k = 0; k < 4; k++) v4[k] = ap[k];
        const float* vv = (const float*)v4;
#pragma unroll
        for (int i = 0; i < 2; i++) {
            int c8 = qq * 2 + i;
            f16x8 w;
#pragma unroll
            for (int j = 0; j < 8; j++) w[j] = (_Float16)vv[i * 8 + j];
            *(f16x8*)&aLDS[(c8 * 64 + m) * 8] = w;
        }
    }

    // alpha (already normalized), contiguous in sorted order
    alphaS[h][lane] = eperm[(size_t)h * N_EDGES + p0 + lane];

    __syncthreads();

    f16x8 wf[2][4];
#pragma unroll
    for (int kt = 0; kt < 2; kt++)
#pragma unroll
        for (int nt = 0; nt < 4; nt++)
            wf[kt][nt] = *(const f16x8*)&Wefrag[(size_t)(((h * 2 + kt) * 4 + nt) * 64 + lane) * 8];

    f32x4 acc[4][4];
#pragma unroll
    for (int mt = 0; mt < 4; mt++)
#pragma unroll
        for (int nt = 0; nt < 4; nt++) acc[mt][nt] = (f32x4)0.f;

#pragma unroll
    for (int kt = 0; kt < 2; kt++) {
        f16x8 afr[4];
#pragma unroll
        for (int mt = 0; mt < 4; mt++)
            afr[mt] = *(f16x8*)&aLDS[((kt * 4 + q) * 64 + mt * 16 + l15) * 8];
#pragma unroll
        for (int mt = 0; mt < 4; mt++)
#pragma unroll
            for (int nt = 0; nt < 4; nt++)
                acc[mt][nt] = __builtin_amdgcn_mfma_f32_16x16x32_f16(afr[mt], wf[kt][nt], acc[mt][nt], 0, 0, 0);
    }

    __syncthreads();   // all waves done reading aLDS before msgS overwrites it

    const float beL = b_edge[h * OUT_F + lane];
    int cur = dstS[0];
    float accv = 0.f;

#pragma unroll
    for (int half = 0; half < 2; half++) {
        // transpose this half's msg (ez part) into LDS: [h][elh][col], pad 66
        // (row stride 66: q-groups offset by 8 banks -> uniform 2-way = free)
#pragma unroll
        for (int mh = 0; mh < 2; mh++) {
            const int mt = half * 2 + mh;
#pragma unroll
            for (int r = 0; r < 4; r++) {
                const int elh = mh * 16 + q * 4 + r;
#pragma unroll
                for (int nt = 0; nt < 4; nt++)
                    smem[(h * 32 + elh) * 66 + nt * 16 + l15] = acc[mt][nt][r];
            }
        }
        __syncthreads();

        // prefetch all 32 z[src] gathers for this half (static unroll -> regs)
        float zf[32];
#pragma unroll
        for (int i = 0; i < 32; i++)
            zf[i] = (float)zb[((size_t)h * N_NODES + srcS[half * 32 + i]) * OUT_F + lane];

        // segmented reduce: lane owns column o=lane; run boundary -> one atomic row
#pragma unroll
        for (int i = 0; i < 32; i++) {
            const int el = half * 32 + i;
            const int d = dstS[el];
            const float msg = smem[(h * 32 + i) * 66 + lane];
            const float al = alphaS[h][el];
            if (d != cur) {
                atomicAdd(&out[(size_t)cur * (NH * OUT_F) + h * OUT_F + lane], accv);
                accv = 0.f;
                cur = d;
            }
            accv += al * (msg + beL + zf[i]);
        }
        __syncthreads();   // reduce reads done before next half overwrites msgS
    }
    atomicAdd(&out[(size_t)cur * (NH * OUT_F) + h * OUT_F + lane], accv);
}

extern "C" void kernel_launch(void* const* d_in, const int* in_sizes, int n_in,
                              void* d_out, int out_size, void* d_ws, size_t ws_size,
                              hipStream_t stream) {
    const float* x         = (const float*)d_in[0];
    const int*   edge_index= (const int*)  d_in[1];
    const float* edge_attr = (const float*)d_in[2];
    const float* W_fc      = (const float*)d_in[3];
    const float* b_fc      = (const float*)d_in[4];
    const float* W_att     = (const float*)d_in[5];
    const float* b_att     = (const float*)d_in[6];
    const float* W_edge    = (const float*)d_in[7];
    const float* b_edge    = (const float*)d_in[8];
    const float* W_eatt    = (const float*)d_in[9];
    const float* b_eatt    = (const float*)d_in[10];

    float* out  = (float*)d_out;                          // (N, H*OUT)
    float* ebuf = out + (size_t)N_NODES * NH * OUT_F;     // (H, E): alpha (original order)

    // ws layout (all chunks 16B-aligned by construction)
    _Float16* zb   = (_Float16*)d_ws;                       // NH*N*64 f16 = 25.6MB
    float* a_i     = (float*)(zb + (size_t)NH * N_NODES * OUT_F);
    float* a_j     = a_i + NH * N_NODES;
    float* eperm   = a_j + NH * N_NODES;                    // (H, E) dst-sorted logits->alpha
    float* u       = eperm + (size_t)NH * N_EDGES;          // H*64
    float* c       = u + NH * 64;                           // H
    int* deg       = (int*)(c + NH);
    int* cursor    = deg + N_NODES;
    int* row_ptr   = cursor + N_NODES;                      // N+1 used, N+16 reserved
    int* eorig     = row_ptr + (N_NODES + 16);
    int* ssrc      = eorig + N_EDGES;
    int* sdst      = ssrc + N_EDGES;
    int* bsum      = sdst + N_EDGES;                        // 256 ints
    _Float16* Wfcfrag = (_Float16*)(bsum + 256);            // H*8*4*64*8 halves
    _Float16* Wefrag  = Wfcfrag + NH * 8 * 4 * 64 * 8;      // H*2*4*64*8 halves
    size_t need = (size_t)((char*)(Wefrag + NH * 2 * 4 * 64 * 8) - (char*)d_ws);

    hipMemsetAsync(out, 0, (size_t)N_NODES * NH * OUT_F * sizeof(float), stream);

    if (ws_size < need) {
        // graceful finite-absmax failure instead of OOB fault (canary)
        hipMemsetAsync(ebuf, 0, (size_t)NH * N_EDGES * sizeof(float), stream);
        return;
    }

    hipMemsetAsync(deg, 0, N_NODES * sizeof(int), stream);

    prep_kernel<<<41, 256, 0, stream>>>(W_att, b_att, W_eatt, b_eatt, W_fc, W_edge,
                                        u, c, Wfcfrag, Wefrag);

    hist_kernel<<<(N_EDGES + 255) / 256, 256, 0, stream>>>(edge_index, deg);
    scan1_kernel<<<SCAN_NB, 256, 0, stream>>>(deg, row_ptr, bsum);
    scan2_kernel<<<1, 256, 0, stream>>>(bsum);
    scan3_kernel<<<SCAN_NB, 256, 0, stream>>>(bsum, row_ptr, cursor);
    scatter_kernel<<<(N_EDGES + 255) / 256, 256, 0, stream>>>(edge_index, cursor,
                                                              eorig, ssrc, sdst);

    z_gemm<<<(N_NODES + 63) / 64, 256, 0, stream>>>(x, Wfcfrag, b_fc, W_att,
                                                    zb, a_i, a_j);

    logits_kernel<<<(N_EDGES + 255) / 256, 256, 0, stream>>>(ssrc, sdst, eorig, edge_attr,
                                                             u, c, a_i, a_j, eperm);

    dim3 sg((N_NODES + 255) / 256, NH);
    softmax_kernel<<<sg, 256, 0, stream>>>(row_ptr, eorig, eperm, ebuf);

    aggregate_mfma<<<N_EDGES / 64, 256, 0, stream>>>(ssrc, sdst, eorig, edge_attr,
                                                     Wefrag, b_edge, zb, eperm, out);
}